// Round 2
// 257.265 us; speedup vs baseline: 1.0683x; 1.0683x over previous
//
#include <hip/hip_runtime.h>
#include <math.h>

#define NH 8
#define HD 64
#define NSEQ 1024
#define DMODEL 512
#define F3 1536
#define NTOK 16384
#define BH 128    // (B*T)*NH = 16*8
#define KVP 72    // attn K/V LDS pitch (bf16)
#define TP 136    // qkv epilogue transpose pitch (bf16)
#define QSCALE 0.1803368867f  // 0.125 * log2(e), folded into q; p = exp2(s')

typedef __attribute__((ext_vector_type(8))) short bf16x8;
typedef __attribute__((ext_vector_type(4))) float f32x4;
typedef __attribute__((ext_vector_type(16))) float f32x16;
typedef __attribute__((ext_vector_type(4))) unsigned int u32x4;
#define MFMA16(a, b, c) __builtin_amdgcn_mfma_f32_16x16x32_bf16(a, b, c, 0, 0, 0)
#define MFMA32(a, b, c) __builtin_amdgcn_mfma_f32_32x32x16_bf16(a, b, c, 0, 0, 0)

__device__ __forceinline__ float freq_of(int j) {
    return 3.14159265358979323846f * (1.0f + (float)j * (127.0f / 15.0f));
}
__device__ __forceinline__ unsigned short bf16_hi(float x) {
    unsigned u = __builtin_bit_cast(unsigned, x);
    return (unsigned short)(u >> 16);   // truncation split; residual goes to lo
}
__device__ __forceinline__ unsigned short bf16_rtn(float x) {
    unsigned u = __builtin_bit_cast(unsigned, x);
    return (unsigned short)((u + 0x7FFF + ((u >> 16) & 1)) >> 16);  // round-nearest-even
}
__device__ __forceinline__ float bf16_tofloat(unsigned short h) {
    unsigned u = ((unsigned)h) << 16;
    return __builtin_bit_cast(float, u);
}
// 2-bit LDS swizzle key for row r (permutes 16-B col-groups within a 64-B row)
__device__ __forceinline__ int swz(int r) { return (r & 3) ^ ((r >> 2) & 3); }

// ---------------- Kernel 0a: split fp32 -> bf16 hi/lo (trunc) ----------------
__global__ __launch_bounds__(256) void split_kernel(
        const float* __restrict__ src, unsigned short* __restrict__ hi,
        unsigned short* __restrict__ lo) {
    const int i = blockIdx.x * 256 + threadIdx.x;
    const float4 v = ((const float4*)src)[i];
    ushort4 h, l;
    h.x = bf16_hi(v.x); l.x = bf16_hi(v.x - bf16_tofloat(h.x));
    h.y = bf16_hi(v.y); l.y = bf16_hi(v.y - bf16_tofloat(h.y));
    h.z = bf16_hi(v.z); l.z = bf16_hi(v.z - bf16_tofloat(h.z));
    h.w = bf16_hi(v.w); l.w = bf16_hi(v.w - bf16_tofloat(h.w));
    ((ushort4*)hi)[i] = h;
    ((ushort4*)lo)[i] = l;
}
// ---------------- Kernel 0b: fp32 -> bf16 RTN single plane ----------------
__global__ __launch_bounds__(256) void cvt_kernel(
        const float* __restrict__ src, unsigned short* __restrict__ dst) {
    const int i = blockIdx.x * 256 + threadIdx.x;
    const float4 v = ((const float4*)src)[i];
    ((ushort4*)dst)[i] = make_ushort4(bf16_rtn(v.x), bf16_rtn(v.y),
                                      bf16_rtn(v.z), bf16_rtn(v.w));
}

// ---- register-staged pipelined GEMM core: 128x128 tile, BK=32, 4 waves ----
// PLANES=3: {A_hi, A_lo, B}; PLANES=2: {A, B}. Global->VGPR loads for kt+1
// issued BEFORE compute(kt); ds_write after; one barrier/iter.
template<int PLANES>
__device__ __forceinline__ void gemm_reg_pipe(
        const unsigned short* __restrict__ a_hi, const unsigned short* __restrict__ a_lo,
        const unsigned short* __restrict__ b_bf,
        char* lds, int m0, int f0, int t, f32x4 acc[4][4]) {
    const int w = t >> 6, lane = t & 63, l15 = lane & 15, quad = lane >> 4;
    const int mw = (w & 1) * 64, nw = (w >> 1) * 64;
    const int STAGE = PLANES * 4096;      // elements per stage
    const int r = t >> 1;                 // 0..127: row this thread stages
    const int g0 = (t & 1) * 2;           // first of two 16-B col-groups

    uint4 regs[PLANES][2];
    auto load_regs = [&](int kt) {
        const int k0 = kt * 32;
        #pragma unroll
        for (int p = 0; p < PLANES; p++) {
            const unsigned short* src =
                (p == 0) ? a_hi : ((p == PLANES - 1) ? b_bf : a_lo);
            const int row0 = (p == PLANES - 1) ? f0 : m0;
            const unsigned short* g = src + (size_t)(row0 + r) * DMODEL + k0 + g0 * 8;
            regs[p][0] = *(const uint4*)g;
            regs[p][1] = *(const uint4*)(g + 8);
        }
    };
    auto store_lds = [&](int stage) {
        unsigned short* S = (unsigned short*)lds + stage * STAGE;
        const int s0 = ((g0 ^ swz(r))) * 8;
        const int s1 = (((g0 + 1) ^ swz(r))) * 8;
        #pragma unroll
        for (int p = 0; p < PLANES; p++) {
            unsigned short* Sp = S + p * 4096 + r * 32;
            *(uint4*)&Sp[s0] = regs[p][0];
            *(uint4*)&Sp[s1] = regs[p][1];
        }
    };

    load_regs(0);
    store_lds(0);
    for (int kt = 0; kt < 16; kt++) {
        __syncthreads();                  // stage (kt&1) visible to all waves
        if (kt < 15) load_regs(kt + 1);   // issue next tile's global loads NOW
        const unsigned short* S = (const unsigned short*)lds + (kt & 1) * STAGE;
        bf16x8 ah[4], al[4], bb[4];
        #pragma unroll
        for (int mt = 0; mt < 4; mt++) {
            const int rr = mw + mt * 16 + l15;
            const int off = rr * 32 + (quad ^ swz(rr)) * 8;
            ah[mt] = *(const bf16x8*)&S[off];
            if (PLANES == 3) al[mt] = *(const bf16x8*)&S[4096 + off];
        }
        #pragma unroll
        for (int nt = 0; nt < 4; nt++) {
            const int rr = nw + nt * 16 + l15;
            bb[nt] = *(const bf16x8*)&S[(PLANES - 1) * 4096 + rr * 32
                                        + (quad ^ swz(rr)) * 8];
        }
        #pragma unroll
        for (int mt = 0; mt < 4; mt++)
            #pragma unroll
            for (int nt = 0; nt < 4; nt++) {
                acc[mt][nt] = MFMA16(ah[mt], bb[nt], acc[mt][nt]);
                if (PLANES == 3) acc[mt][nt] = MFMA16(al[mt], bb[nt], acc[mt][nt]);
            }
        if (kt < 15) store_lds((kt + 1) & 1);  // vmcnt wait lands here, post-MFMA
    }
    __syncthreads();                      // LDS free for epilogue reuse
}

// ---------------- Kernel 1: QKV GEMM + RoPE (128x128 tile) ----------------
// Outputs: q_bf (RTN, QSCALE folded), k_bf (RTN), v_th (RTN, transposed).
__global__ __launch_bounds__(256, 3) void qkv_mfma_kernel(
        const unsigned short* __restrict__ x_hi, const unsigned short* __restrict__ x_lo,
        const unsigned short* __restrict__ wq_bf,
        unsigned short* __restrict__ q_bf, unsigned short* __restrict__ k_bf,
        unsigned short* __restrict__ v_th) {
    __shared__ __align__(16) char lds[49152 + 4608];   // 2x24KB stages (+T alias) + tables
    unsigned short* T = (unsigned short*)lds;          // 128 x TP transpose buffer
    float* t_cy = (float*)(lds + 49152);               // [4][16]
    float* t_sy = t_cy + 64;
    float* t_cx = t_sy + 64;                           // [32][16]
    float* t_sx = t_cx + 512;

    const int m0 = blockIdx.x * 128;
    const int f0 = blockIdx.y * 128;
    const int t = threadIdx.x;
    const int w = t >> 6, lane = t & 63, l15 = lane & 15, quad = lane >> 4;
    const int mw = (w & 1) * 64, nw = (w >> 1) * 64;
    const int sel = f0 >> 9;                // 0=q,1=k,2=v
    const int bt = m0 >> 10;
    const int n0 = m0 & 1023;

    if (sel != 2) {
        for (int idx = t; idx < 576; idx += 256) {
            if (idx < 64) {
                const int yi = idx >> 4, j = idx & 15;
                const float pos = -1.0f + (float)((n0 >> 5) + yi) * (2.0f / 31.0f);
                float sv, cv; sincosf(pos * freq_of(j), &sv, &cv);
                t_sy[idx] = sv; t_cy[idx] = cv;
            } else {
                const int k2 = idx - 64, xi = k2 >> 4, j = k2 & 15;
                const float pos = -1.0f + (float)xi * (2.0f / 31.0f);
                float sv, cv; sincosf(pos * freq_of(j), &sv, &cv);
                t_sx[k2] = sv; t_cx[k2] = cv;
            }
        }
    }
    __syncthreads();

    f32x4 acc[4][4];
    #pragma unroll
    for (int mt = 0; mt < 4; mt++)
        #pragma unroll
        for (int nt = 0; nt < 4; nt++) acc[mt][nt] = (f32x4){0.f, 0.f, 0.f, 0.f};

    gemm_reg_pipe<3>(x_hi, x_lo, wq_bf, lds, m0, f0, t, acc);

    // rope in place (q,k); q additionally scaled by QSCALE so attn uses exp2
    if (sel != 2) {
        const float post = (sel == 0) ? QSCALE : 1.0f;
        #pragma unroll
        for (int mt = 0; mt < 4; mt++)
            #pragma unroll
            for (int nt = 0; nt < 4; nt++)
                #pragma unroll
                for (int rr = 0; rr < 4; rr++) {
                    const int ml = mw + mt * 16 + quad * 4 + rr;
                    const int dd = (nw + nt * 16 + l15) & 63;
                    const int j0 = (dd & 31) >> 1;
                    float c, s;
                    if (dd < 32) { c = t_cy[(ml >> 5) * 16 + j0]; s = t_sy[(ml >> 5) * 16 + j0]; }
                    else         { c = t_cx[(ml & 31) * 16 + j0]; s = t_sx[(ml & 31) * 16 + j0]; }
                    const float v = acc[mt][nt][rr];
                    const float pv = __shfl_xor(v, 1);
                    acc[mt][nt][rr] = ((l15 & 1) ? (v * c + pv * s) : (v * c - pv * s)) * post;
                }
    }

    // single RTN pass through T; v transposed, q/k row-major
    if (sel == 2) {
        #pragma unroll
        for (int mt = 0; mt < 4; mt++)
            #pragma unroll
            for (int nt = 0; nt < 4; nt++) {
                const int fl = nw + nt * 16 + l15;
                const int mlb = mw + mt * 16 + quad * 4;
                ushort4 pk = make_ushort4(
                    bf16_rtn(acc[mt][nt][0]), bf16_rtn(acc[mt][nt][1]),
                    bf16_rtn(acc[mt][nt][2]), bf16_rtn(acc[mt][nt][3]));
                *(ushort4*)&T[fl * TP + mlb] = pk;
            }
    } else {
        #pragma unroll
        for (int mt = 0; mt < 4; mt++)
            #pragma unroll
            for (int nt = 0; nt < 4; nt++)
                #pragma unroll
                for (int rr = 0; rr < 4; rr++) {
                    const int ml = mw + mt * 16 + quad * 4 + rr;
                    const int fl = nw + nt * 16 + l15;
                    T[ml * TP + fl] = bf16_rtn(acc[mt][nt][rr]);
                }
    }
    __syncthreads();
    if (sel == 2) {
        #pragma unroll
        for (int p = 0; p < 8; p++) {
            const int idx = p * 256 + t;
            const int fl = idx >> 4, g8 = (idx & 15) * 8;
            const int head = ((f0 + fl) >> 6) & 7;
            *(uint4*)(v_th + ((size_t)(bt * NH + head) * HD + ((f0 + fl) & 63)) * NSEQ
                      + n0 + g8) = *(const uint4*)&T[fl * TP + g8];
        }
    } else {
        unsigned short* dst = (sel == 0) ? q_bf : k_bf;
        #pragma unroll
        for (int p = 0; p < 8; p++) {
            const int idx = p * 256 + t;
            const int ml = idx >> 4, g8 = (idx & 15) * 8;
            const int head = ((f0 + g8) >> 6) & 7;
            *(uint4*)(dst + ((size_t)(bt * NH + head) * NSEQ + n0 + ml) * HD
                      + ((f0 + g8) & 63)) = *(const uint4*)&T[ml * TP + g8];
        }
    }
    __syncthreads();
}

// ---------------- Kernel 2: flash attention, swapped-QK^T 32x32, in-register P ----
// S^T = mfma32(K, Q): lane owns one q-row (lane&31), 16 k-cols (crow(r,hi)).
// p = exp2(s) -> v_cvt_pk_bf16_f32 pairs -> v_permlane32_swap builds PV A-frags
// entirely in registers (no P LDS round-trip). Row-sum l via ones-B MFMA lands
// in the same C-distribution as O. K/V double-buffered through registers.
// Grid is (bh, qt) so the 8 qt-blocks sharing one bh's K/V land on one XCD.
__global__ __launch_bounds__(256, 3) void attn_kernel(
        const unsigned short* __restrict__ q_bf, const unsigned short* __restrict__ k_bf,
        const unsigned short* __restrict__ v_th,
        unsigned short* __restrict__ o_bf) {
    __shared__ unsigned short Ks[2][64 * KVP];  // K tile [n][d], double-buffered
    __shared__ unsigned short Vs[2][64 * KVP];  // V^T tile [d][n], double-buffered

    const int bh = blockIdx.x;     // fastest dim -> XCD = bh & 7 for all 8 qt blocks
    const int qt = blockIdx.y;     // 0..7
    const int t = threadIdx.x;
    const int w = t >> 6;
    const int lane = t & 63;
    const int l31 = lane & 31;
    const int hi = lane >> 5;

    const size_t bh_nd = (size_t)bh * NSEQ * HD;
    const size_t bh_dn = (size_t)bh * HD * NSEQ;

    // Q as B-fragments of mfma32 (B[k=d][col=qrow]): lane reads
    // Q[qrow = w*32 + l31][d = ds*16 + hi*8 + 0..7]; loaded once per block.
    bf16x8 qfB[4];
    {
        const size_t rbase = bh_nd + (size_t)(qt * 128 + w * 32 + l31) * HD + hi * 8;
        #pragma unroll
        for (int ds = 0; ds < 4; ds++)
            qfB[ds] = *(const bf16x8*)(q_bf + rbase + ds * 16);
    }

    uint4 kr[2], vr[2];
    auto load_kv = [&](int kt) {
        #pragma unroll
        for (int p = 0; p < 2; p++) {
            const int cc = t + p * 256;
            const int r = cc >> 3, off8 = (cc & 7) * 8;
            kr[p] = *(const uint4*)(k_bf + bh_nd + (size_t)(kt * 64 + r) * HD + off8);
            vr[p] = *(const uint4*)(v_th + bh_dn + (size_t)r * NSEQ + kt * 64 + off8);
        }
    };
    auto store_kv = [&](int st) {
        #pragma unroll
        for (int p = 0; p < 2; p++) {
            const int cc = t + p * 256;
            const int r = cc >> 3, off8 = (cc & 7) * 8;
            *(uint4*)&Ks[st][r * KVP + off8] = kr[p];
            *(uint4*)&Vs[st][r * KVP + off8] = vr[p];
        }
    };

    const bf16x8 ones = {(short)0x3F80, (short)0x3F80, (short)0x3F80, (short)0x3F80,
                         (short)0x3F80, (short)0x3F80, (short)0x3F80, (short)0x3F80};

    f32x16 o_acc[2], l_acc;
    #pragma unroll
    for (int i = 0; i < 16; i++) {
        o_acc[0][i] = 0.f; o_acc[1][i] = 0.f; l_acc[i] = 0.f;
    }

    load_kv(0);
    store_kv(0);
    for (int kt = 0; kt < 16; kt++) {
        __syncthreads();                  // stage (kt&1) visible
        if (kt < 15) load_kv(kt + 1);     // prefetch next tile into VGPRs
        const unsigned short* K = Ks[kt & 1];
        const unsigned short* V = Vs[kt & 1];

        #pragma unroll
        for (int nt2 = 0; nt2 < 2; nt2++) {
            // ---- S^T = K · Q^T over d=64 (4 chained K=16 MFMAs) ----
            f32x16 s;
            #pragma unroll
            for (int i = 0; i < 16; i++) s[i] = 0.f;
            #pragma unroll
            for (int ds = 0; ds < 4; ds++) {
                const bf16x8 kb =
                    *(const bf16x8*)&K[(nt2 * 32 + l31) * KVP + ds * 16 + hi * 8];
                s = MFMA32(kb, qfB[ds], s);
            }

            // ---- p = exp2(s); pack pairs to bf16 words ----
            // lane holds P[qrow=l31][kcol = crow(r,hi)], crow = (r&3)+8*(r>>2)+4*hi
            unsigned wv[8];
            #pragma unroll
            for (int i = 0; i < 8; i++) {
                const float p0 = exp2f(s[2 * i]);
                const float p1 = exp2f(s[2 * i + 1]);
                asm("v_cvt_pk_bf16_f32 %0, %1, %2" : "=v"(wv[i]) : "v"(p0), "v"(p1));
            }
            // ---- exchange halves: vdst.hi <-> vsrc.lo (first operand = lower-k word)
            // swap(w0,w2): w0 = {w0.lo, w2.lo} = frag word0; w2 = {w0.hi, w2.hi} = word2
            asm volatile("v_permlane32_swap_b32 %0, %1" : "+v"(wv[0]), "+v"(wv[2]));
            asm volatile("v_permlane32_swap_b32 %0, %1" : "+v"(wv[1]), "+v"(wv[3]));
            asm volatile("v_permlane32_swap_b32 %0, %1" : "+v"(wv[4]), "+v"(wv[6]));
            asm volatile("v_permlane32_swap_b32 %0, %1" : "+v"(wv[5]), "+v"(wv[7]));

            // ---- O += P·V, l += P·1 (P entirely in registers) ----
            #pragma unroll
            for (int k2 = 0; k2 < 2; k2++) {
                const u32x4 paw = {wv[k2 * 4 + 0], wv[k2 * 4 + 1],
                                   wv[k2 * 4 + 2], wv[k2 * 4 + 3]};
                const bf16x8 pa = __builtin_bit_cast(bf16x8, paw);
                const int kstep = nt2 * 2 + k2;
                l_acc = MFMA32(pa, ones, l_acc);
                #pragma unroll
                for (int dt = 0; dt < 2; dt++) {
                    const bf16x8 vb =
                        *(const bf16x8*)&V[(dt * 32 + l31) * KVP + kstep * 16 + hi * 8];
                    o_acc[dt] = MFMA32(pa, vb, o_acc[dt]);
                }
            }
        }
        if (kt < 15) store_kv((kt + 1) & 1);  // vmcnt wait lands post-MFMA
    }

    // ---- epilogue: normalize by l; 64-B aligned store segments ----
    const int btq = bh >> 3, head = bh & 7;
    #pragma unroll
    for (int r = 0; r < 16; r++) {
        const float inv = 1.0f / l_acc[r];
        const int row = qt * 128 + w * 32 + (r & 3) + 8 * (r >> 2) + 4 * hi;
        #pragma unroll
        for (int dt = 0; dt < 2; dt++) {
            o_bf[((size_t)(btq * NSEQ + row)) * DMODEL + head * HD + dt * 32 + l31] =
                bf16_rtn(o_acc[dt][r] * inv);
        }
    }
}

// ---------------- Kernel 3: output projection (2-plane, pipelined) ----------------
__global__ __launch_bounds__(256, 3) void proj_mfma_kernel(
        const unsigned short* __restrict__ o_bf,
        const unsigned short* __restrict__ wo_bf,
        const float* __restrict__ b_out, float* __restrict__ out) {
    __shared__ __align__(16) char lds[32768];   // 2 x 16KB stages

    const int m0 = blockIdx.x * 128;
    const int f0 = blockIdx.y * 128;
    const int t = threadIdx.x;
    const int w = t >> 6, lane = t & 63, l15 = lane & 15, quad = lane >> 4;
    const int mw = (w & 1) * 64, nw = (w >> 1) * 64;

    f32x4 acc[4][4];
    #pragma unroll
    for (int mt = 0; mt < 4; mt++)
        #pragma unroll
        for (int nt = 0; nt < 4; nt++) acc[mt][nt] = (f32x4){0.f, 0.f, 0.f, 0.f};

    gemm_reg_pipe<2>(o_bf, o_bf, wo_bf, lds, m0, f0, t, acc);

    float bias_v[4];
    #pragma unroll
    for (int nt = 0; nt < 4; nt++) bias_v[nt] = b_out[f0 + nw + nt * 16 + l15];
    #pragma unroll
    for (int mt = 0; mt < 4; mt++)
        #pragma unroll
        for (int nt = 0; nt < 4; nt++)
            #pragma unroll
            for (int rr = 0; rr < 4; rr++) {
                const int m = m0 + mw + mt * 16 + quad * 4 + rr;
                out[(size_t)m * DMODEL + f0 + nw + nt * 16 + l15] =
                    acc[mt][nt][rr] + bias_v[nt];
            }
}

extern "C" void kernel_launch(void* const* d_in, const int* in_sizes, int n_in,
                              void* d_out, int out_size, void* d_ws, size_t ws_size,
                              hipStream_t stream) {
    const float* x  = (const float*)d_in[0];
    const float* wq = (const float*)d_in[1];
    const float* wo = (const float*)d_in[2];
    const float* bo = (const float*)d_in[3];
    float* out = (float*)d_out;

    const size_t per = (size_t)BH * NSEQ * HD;   // 8,388,608 elements
    unsigned short* x_hi = (unsigned short*)d_ws;   // reused as o_bf after qkv
    unsigned short* x_lo = x_hi + per;
    unsigned short* q_bf = x_lo + per;
    unsigned short* k_bf = q_bf + per;
    unsigned short* v_th = k_bf + per;
    unsigned short* wq_bf = v_th + per;                   // 786,432 els
    unsigned short* wo_bf = wq_bf + (size_t)F3 * DMODEL;  // 262,144 els (~82 MiB total)
    unsigned short* o_bf = x_hi;   // x dead after qkv

    split_kernel<<<dim3((int)(per / 1024)), 256, 0, stream>>>(x, x_hi, x_lo);
    cvt_kernel<<<dim3(F3 * DMODEL / 1024), 256, 0, stream>>>(wq, wq_bf);
    cvt_kernel<<<dim3(DMODEL * DMODEL / 1024), 256, 0, stream>>>(wo, wo_bf);
    qkv_mfma_kernel<<<dim3(NTOK / 128, F3 / 128), 256, 0, stream>>>(
        x_hi, x_lo, wq_bf, q_bf, k_bf, v_th);
    attn_kernel<<<dim3(BH, 8), 256, 0, stream>>>(
        q_bf, k_bf, v_th, o_bf);
    proj_mfma_kernel<<<dim3(NTOK / 128, DMODEL / 128), 256, 0, stream>>>(
        o_bf, wo_bf, bo, out);
}

// Round 3
// 252.927 us; speedup vs baseline: 1.0866x; 1.0172x over previous
//
#include <hip/hip_runtime.h>
#include <math.h>

#define NH 8
#define HD 64
#define NSEQ 1024
#define DMODEL 512
#define F3 1536
#define NTOK 16384
#define BH 128    // (B*T)*NH = 16*8
#define KVP 72    // attn K/V LDS pitch (bf16)
#define TP 136    // qkv epilogue transpose pitch (bf16)
#define QSCALE 0.1803368867f  // 0.125 * log2(e), folded into q; p = exp2(s')

typedef __attribute__((ext_vector_type(8))) short bf16x8;
typedef __attribute__((ext_vector_type(4))) float f32x4;
typedef __attribute__((ext_vector_type(16))) float f32x16;
typedef __attribute__((ext_vector_type(4))) unsigned int u32x4;
#define MFMA16(a, b, c) __builtin_amdgcn_mfma_f32_16x16x32_bf16(a, b, c, 0, 0, 0)
#define MFMA32(a, b, c) __builtin_amdgcn_mfma_f32_32x32x16_bf16(a, b, c, 0, 0, 0)

__device__ __forceinline__ float freq_of(int j) {
    return 3.14159265358979323846f * (1.0f + (float)j * (127.0f / 15.0f));
}
__device__ __forceinline__ unsigned short bf16_hi(float x) {
    unsigned u = __builtin_bit_cast(unsigned, x);
    return (unsigned short)(u >> 16);   // truncation split; residual goes to lo
}
__device__ __forceinline__ unsigned short bf16_rtn(float x) {
    unsigned u = __builtin_bit_cast(unsigned, x);
    return (unsigned short)((u + 0x7FFF + ((u >> 16) & 1)) >> 16);  // round-nearest-even
}
__device__ __forceinline__ float bf16_tofloat(unsigned short h) {
    unsigned u = ((unsigned)h) << 16;
    return __builtin_bit_cast(float, u);
}
// 2-bit LDS swizzle key for row r (permutes 16-B col-groups within a 64-B row)
__device__ __forceinline__ int swz(int r) { return (r & 3) ^ ((r >> 2) & 3); }

// ---------------- Kernel 0a: split fp32 -> bf16 hi/lo (trunc) ----------------
__global__ __launch_bounds__(256) void split_kernel(
        const float* __restrict__ src, unsigned short* __restrict__ hi,
        unsigned short* __restrict__ lo) {
    const int i = blockIdx.x * 256 + threadIdx.x;
    const float4 v = ((const float4*)src)[i];
    ushort4 h, l;
    h.x = bf16_hi(v.x); l.x = bf16_hi(v.x - bf16_tofloat(h.x));
    h.y = bf16_hi(v.y); l.y = bf16_hi(v.y - bf16_tofloat(h.y));
    h.z = bf16_hi(v.z); l.z = bf16_hi(v.z - bf16_tofloat(h.z));
    h.w = bf16_hi(v.w); l.w = bf16_hi(v.w - bf16_tofloat(h.w));
    ((ushort4*)hi)[i] = h;
    ((ushort4*)lo)[i] = l;
}
// ---------------- Kernel 0b: fp32 -> bf16 RTN single plane ----------------
__global__ __launch_bounds__(256) void cvt_kernel(
        const float* __restrict__ src, unsigned short* __restrict__ dst) {
    const int i = blockIdx.x * 256 + threadIdx.x;
    const float4 v = ((const float4*)src)[i];
    ((ushort4*)dst)[i] = make_ushort4(bf16_rtn(v.x), bf16_rtn(v.y),
                                      bf16_rtn(v.z), bf16_rtn(v.w));
}

// ---- register-staged pipelined GEMM core: 128x(128*NREP) tile, BK=32, 4 waves ----
// A planes = PLANES-1 ({A_hi,A_lo} or {A}); B planes = NREP (f0, f0+128, ...).
// Global->VGPR loads for kt+1 issued BEFORE compute(kt); ds_write after; one
// barrier/iter.
template<int PLANES, int NREP>
__device__ __forceinline__ void gemm_reg_pipe(
        const unsigned short* __restrict__ a_hi, const unsigned short* __restrict__ a_lo,
        const unsigned short* __restrict__ b_bf,
        char* lds, int m0, int f0, int t, f32x4 (&acc)[NREP][4][4]) {
    const int w = t >> 6, lane = t & 63, l15 = lane & 15, quad = lane >> 4;
    const int mw = (w & 1) * 64, nw = (w >> 1) * 64;
    const int APL = PLANES - 1;           // A planes
    const int NPL = APL + NREP;           // total planes
    const int STAGE = NPL * 4096;         // elements per stage
    const int r = t >> 1;                 // 0..127: row this thread stages
    const int g0 = (t & 1) * 2;           // first of two 16-B col-groups

    uint4 regs[NPL][2];
    auto load_regs = [&](int kt) {
        const int k0 = kt * 32;
        #pragma unroll
        for (int p = 0; p < NPL; p++) {
            const unsigned short* src = (p < APL) ? (p == 0 ? a_hi : a_lo) : b_bf;
            const int row0 = (p < APL) ? m0 : (f0 + (p - APL) * 128);
            const unsigned short* g = src + (size_t)(row0 + r) * DMODEL + k0 + g0 * 8;
            regs[p][0] = *(const uint4*)g;
            regs[p][1] = *(const uint4*)(g + 8);
        }
    };
    auto store_lds = [&](int stage) {
        unsigned short* S = (unsigned short*)lds + stage * STAGE;
        const int s0 = ((g0 ^ swz(r))) * 8;
        const int s1 = (((g0 + 1) ^ swz(r))) * 8;
        #pragma unroll
        for (int p = 0; p < NPL; p++) {
            unsigned short* Sp = S + p * 4096 + r * 32;
            *(uint4*)&Sp[s0] = regs[p][0];
            *(uint4*)&Sp[s1] = regs[p][1];
        }
    };

    load_regs(0);
    store_lds(0);
    for (int kt = 0; kt < 16; kt++) {
        __syncthreads();                  // stage (kt&1) visible to all waves
        if (kt < 15) load_regs(kt + 1);   // issue next tile's global loads NOW
        const unsigned short* S = (const unsigned short*)lds + (kt & 1) * STAGE;
        bf16x8 ah[4], al[4];
        #pragma unroll
        for (int mt = 0; mt < 4; mt++) {
            const int rr = mw + mt * 16 + l15;
            const int off = rr * 32 + (quad ^ swz(rr)) * 8;
            ah[mt] = *(const bf16x8*)&S[off];
            if (APL == 2) al[mt] = *(const bf16x8*)&S[4096 + off];
        }
        #pragma unroll
        for (int nr = 0; nr < NREP; nr++) {
            bf16x8 bb[4];
            #pragma unroll
            for (int nt = 0; nt < 4; nt++) {
                const int rr = nw + nt * 16 + l15;
                bb[nt] = *(const bf16x8*)&S[(APL + nr) * 4096 + rr * 32
                                            + (quad ^ swz(rr)) * 8];
            }
            #pragma unroll
            for (int mt = 0; mt < 4; mt++)
                #pragma unroll
                for (int nt = 0; nt < 4; nt++) {
                    acc[nr][mt][nt] = MFMA16(ah[mt], bb[nt], acc[nr][mt][nt]);
                    if (APL == 2) acc[nr][mt][nt] = MFMA16(al[mt], bb[nt], acc[nr][mt][nt]);
                }
        }
        if (kt < 15) store_lds((kt + 1) & 1);  // vmcnt wait lands here, post-MFMA
    }
    __syncthreads();                      // LDS free for epilogue reuse
}

// ---------------- Kernel 1: QKV GEMM + RoPE (128x256 tile, NREP=2) ----------------
// Outputs: q_bf (RTN, QSCALE folded), k_bf (RTN), v_th (RTN, transposed).
__global__ __launch_bounds__(256, 2) void qkv_mfma_kernel(
        const unsigned short* __restrict__ x_hi, const unsigned short* __restrict__ x_lo,
        const unsigned short* __restrict__ wq_bf,
        unsigned short* __restrict__ q_bf, unsigned short* __restrict__ k_bf,
        unsigned short* __restrict__ v_th) {
    __shared__ __align__(16) char lds[65536 + 4608];   // 2x32KB stages (+T alias) + tables
    unsigned short* T = (unsigned short*)lds;          // 128 x TP transpose buffer
    float* t_cy = (float*)(lds + 65536);               // [4][16]
    float* t_sy = t_cy + 64;
    float* t_cx = t_sy + 64;                           // [32][16]
    float* t_sx = t_cx + 512;

    const int m0 = blockIdx.x * 128;
    const int f0 = blockIdx.y * 256;
    const int t = threadIdx.x;
    const int w = t >> 6, lane = t & 63, l15 = lane & 15, quad = lane >> 4;
    const int mw = (w & 1) * 64, nw = (w >> 1) * 64;
    const int sel = f0 >> 9;                // 0=q,1=k,2=v (same for both subtiles)
    const int bt = m0 >> 10;
    const int n0 = m0 & 1023;

    if (sel != 2) {
        for (int idx = t; idx < 576; idx += 256) {
            if (idx < 64) {
                const int yi = idx >> 4, j = idx & 15;
                const float pos = -1.0f + (float)((n0 >> 5) + yi) * (2.0f / 31.0f);
                float sv, cv; sincosf(pos * freq_of(j), &sv, &cv);
                t_sy[idx] = sv; t_cy[idx] = cv;
            } else {
                const int k2 = idx - 64, xi = k2 >> 4, j = k2 & 15;
                const float pos = -1.0f + (float)xi * (2.0f / 31.0f);
                float sv, cv; sincosf(pos * freq_of(j), &sv, &cv);
                t_sx[k2] = sv; t_cx[k2] = cv;
            }
        }
    }
    __syncthreads();

    f32x4 acc[2][4][4];
    #pragma unroll
    for (int nr = 0; nr < 2; nr++)
        #pragma unroll
        for (int mt = 0; mt < 4; mt++)
            #pragma unroll
            for (int nt = 0; nt < 4; nt++) acc[nr][mt][nt] = (f32x4){0.f, 0.f, 0.f, 0.f};

    gemm_reg_pipe<3, 2>(x_hi, x_lo, wq_bf, lds, m0, f0, t, acc);

    #pragma unroll
    for (int nr = 0; nr < 2; nr++) {
        const int fs = f0 + nr * 128;
        // rope in place (q,k); q additionally scaled by QSCALE so attn uses exp2
        if (sel != 2) {
            const float post = (sel == 0) ? QSCALE : 1.0f;
            #pragma unroll
            for (int mt = 0; mt < 4; mt++)
                #pragma unroll
                for (int nt = 0; nt < 4; nt++)
                    #pragma unroll
                    for (int rr = 0; rr < 4; rr++) {
                        const int ml = mw + mt * 16 + quad * 4 + rr;
                        const int dd = (nw + nt * 16 + l15) & 63;
                        const int j0 = (dd & 31) >> 1;
                        float c, s;
                        if (dd < 32) { c = t_cy[(ml >> 5) * 16 + j0]; s = t_sy[(ml >> 5) * 16 + j0]; }
                        else         { c = t_cx[(ml & 31) * 16 + j0]; s = t_sx[(ml & 31) * 16 + j0]; }
                        const float v = acc[nr][mt][nt][rr];
                        const float pv = __shfl_xor(v, 1);
                        acc[nr][mt][nt][rr] =
                            ((l15 & 1) ? (v * c + pv * s) : (v * c - pv * s)) * post;
                    }
        }

        // single RTN pass through T; v transposed, q/k row-major
        if (sel == 2) {
            #pragma unroll
            for (int mt = 0; mt < 4; mt++)
                #pragma unroll
                for (int nt = 0; nt < 4; nt++) {
                    const int fl = nw + nt * 16 + l15;
                    const int mlb = mw + mt * 16 + quad * 4;
                    ushort4 pk = make_ushort4(
                        bf16_rtn(acc[nr][mt][nt][0]), bf16_rtn(acc[nr][mt][nt][1]),
                        bf16_rtn(acc[nr][mt][nt][2]), bf16_rtn(acc[nr][mt][nt][3]));
                    *(ushort4*)&T[fl * TP + mlb] = pk;
                }
        } else {
            #pragma unroll
            for (int mt = 0; mt < 4; mt++)
                #pragma unroll
                for (int nt = 0; nt < 4; nt++)
                    #pragma unroll
                    for (int rr = 0; rr < 4; rr++) {
                        const int ml = mw + mt * 16 + quad * 4 + rr;
                        const int fl = nw + nt * 16 + l15;
                        T[ml * TP + fl] = bf16_rtn(acc[nr][mt][nt][rr]);
                    }
        }
        __syncthreads();
        if (sel == 2) {
            #pragma unroll
            for (int p = 0; p < 8; p++) {
                const int idx = p * 256 + t;
                const int fl = idx >> 4, g8 = (idx & 15) * 8;
                const int head = ((fs + fl) >> 6) & 7;
                *(uint4*)(v_th + ((size_t)(bt * NH + head) * HD + ((fs + fl) & 63)) * NSEQ
                          + n0 + g8) = *(const uint4*)&T[fl * TP + g8];
            }
        } else {
            unsigned short* dst = (sel == 0) ? q_bf : k_bf;
            #pragma unroll
            for (int p = 0; p < 8; p++) {
                const int idx = p * 256 + t;
                const int ml = idx >> 4, g8 = (idx & 15) * 8;
                const int head = ((fs + g8) >> 6) & 7;
                *(uint4*)(dst + ((size_t)(bt * NH + head) * NSEQ + n0 + ml) * HD
                          + ((fs + g8) & 63)) = *(const uint4*)&T[ml * TP + g8];
            }
        }
        __syncthreads();
    }
}

// ---------------- Kernel 2: flash attention, swapped-QK^T 32x32, in-register P ----
// S^T = mfma32(K, Q): lane owns one q-row (lane&31), 16 k-cols (crow(r,hi)).
// p = exp2(s) -> v_cvt_pk_bf16_f32 pairs -> v_permlane32_swap builds PV A-frags
// entirely in registers (no P LDS round-trip). Row-sum l via ones-B MFMA lands
// in the same C-distribution as O. K/V double-buffered through registers.
// Grid is (bh, qt) so the 8 qt-blocks sharing one bh's K/V land on one XCD.
// Epilogue bounces O through LDS (dead Ks region) for full-128B-line stores.
__global__ __launch_bounds__(256, 3) void attn_kernel(
        const unsigned short* __restrict__ q_bf, const unsigned short* __restrict__ k_bf,
        const unsigned short* __restrict__ v_th,
        unsigned short* __restrict__ o_bf) {
    __shared__ unsigned short Ks[2][64 * KVP];  // K tile [n][d], double-buffered
    __shared__ unsigned short Vs[2][64 * KVP];  // V^T tile [d][n], double-buffered

    const int bh = blockIdx.x;     // fastest dim -> XCD = bh & 7 for all 8 qt blocks
    const int qt = blockIdx.y;     // 0..7
    const int t = threadIdx.x;
    const int w = t >> 6;
    const int lane = t & 63;
    const int l31 = lane & 31;
    const int hi = lane >> 5;

    const size_t bh_nd = (size_t)bh * NSEQ * HD;
    const size_t bh_dn = (size_t)bh * HD * NSEQ;

    // Q as B-fragments of mfma32 (B[k=d][col=qrow]): lane reads
    // Q[qrow = w*32 + l31][d = ds*16 + hi*8 + 0..7]; loaded once per block.
    bf16x8 qfB[4];
    {
        const size_t rbase = bh_nd + (size_t)(qt * 128 + w * 32 + l31) * HD + hi * 8;
        #pragma unroll
        for (int ds = 0; ds < 4; ds++)
            qfB[ds] = *(const bf16x8*)(q_bf + rbase + ds * 16);
    }

    uint4 kr[2], vr[2];
    auto load_kv = [&](int kt) {
        #pragma unroll
        for (int p = 0; p < 2; p++) {
            const int cc = t + p * 256;
            const int r = cc >> 3, off8 = (cc & 7) * 8;
            kr[p] = *(const uint4*)(k_bf + bh_nd + (size_t)(kt * 64 + r) * HD + off8);
            vr[p] = *(const uint4*)(v_th + bh_dn + (size_t)r * NSEQ + kt * 64 + off8);
        }
    };
    auto store_kv = [&](int st) {
        #pragma unroll
        for (int p = 0; p < 2; p++) {
            const int cc = t + p * 256;
            const int r = cc >> 3, off8 = (cc & 7) * 8;
            *(uint4*)&Ks[st][r * KVP + off8] = kr[p];
            *(uint4*)&Vs[st][r * KVP + off8] = vr[p];
        }
    };

    const bf16x8 ones = {(short)0x3F80, (short)0x3F80, (short)0x3F80, (short)0x3F80,
                         (short)0x3F80, (short)0x3F80, (short)0x3F80, (short)0x3F80};

    f32x16 o_acc[2], l_acc;
    #pragma unroll
    for (int i = 0; i < 16; i++) {
        o_acc[0][i] = 0.f; o_acc[1][i] = 0.f; l_acc[i] = 0.f;
    }

    load_kv(0);
    store_kv(0);
    for (int kt = 0; kt < 16; kt++) {
        __syncthreads();                  // stage (kt&1) visible
        if (kt < 15) load_kv(kt + 1);     // prefetch next tile into VGPRs
        const unsigned short* K = Ks[kt & 1];
        const unsigned short* V = Vs[kt & 1];

        #pragma unroll
        for (int nt2 = 0; nt2 < 2; nt2++) {
            // ---- S^T = K · Q^T over d=64 (4 chained K=16 MFMAs) ----
            f32x16 s;
            #pragma unroll
            for (int i = 0; i < 16; i++) s[i] = 0.f;
            #pragma unroll
            for (int ds = 0; ds < 4; ds++) {
                const bf16x8 kb =
                    *(const bf16x8*)&K[(nt2 * 32 + l31) * KVP + ds * 16 + hi * 8];
                s = MFMA32(kb, qfB[ds], s);
            }

            // ---- p = exp2(s); pack pairs to bf16 words ----
            // lane holds P[qrow=l31][kcol = crow(r,hi)], crow = (r&3)+8*(r>>2)+4*hi
            unsigned wv[8];
            #pragma unroll
            for (int i = 0; i < 8; i++) {
                const float p0 = exp2f(s[2 * i]);
                const float p1 = exp2f(s[2 * i + 1]);
                asm("v_cvt_pk_bf16_f32 %0, %1, %2" : "=v"(wv[i]) : "v"(p0), "v"(p1));
            }
            // ---- exchange halves: vdst.hi <-> vsrc.lo (first operand = lower-k word)
            // swap(w0,w2): w0 = {w0.lo, w2.lo} = frag word0; w2 = {w0.hi, w2.hi} = word2
            asm volatile("v_permlane32_swap_b32 %0, %1" : "+v"(wv[0]), "+v"(wv[2]));
            asm volatile("v_permlane32_swap_b32 %0, %1" : "+v"(wv[1]), "+v"(wv[3]));
            asm volatile("v_permlane32_swap_b32 %0, %1" : "+v"(wv[4]), "+v"(wv[6]));
            asm volatile("v_permlane32_swap_b32 %0, %1" : "+v"(wv[5]), "+v"(wv[7]));

            // ---- O += P·V, l += P·1 (P entirely in registers) ----
            #pragma unroll
            for (int k2 = 0; k2 < 2; k2++) {
                const u32x4 paw = {wv[k2 * 4 + 0], wv[k2 * 4 + 1],
                                   wv[k2 * 4 + 2], wv[k2 * 4 + 3]};
                const bf16x8 pa = __builtin_bit_cast(bf16x8, paw);
                const int kstep = nt2 * 2 + k2;
                l_acc = MFMA32(pa, ones, l_acc);
                #pragma unroll
                for (int dt = 0; dt < 2; dt++) {
                    const bf16x8 vb =
                        *(const bf16x8*)&V[(dt * 32 + l31) * KVP + kstep * 16 + hi * 8];
                    o_acc[dt] = MFMA32(pa, vb, o_acc[dt]);
                }
            }
        }
        if (kt < 15) store_kv((kt + 1) & 1);  // vmcnt wait lands post-MFMA
    }

    // ---- epilogue: normalize by l; LDS bounce -> full-128B-line uint4 stores ----
    __syncthreads();                       // all waves done reading Ks/Vs
    unsigned short* Osh = &Ks[0][0];       // 128 rows x KVP pitch = 9216 els, exact fit
    #pragma unroll
    for (int r = 0; r < 16; r++) {
        const float inv = 1.0f / l_acc[r];
        const int row = w * 32 + (r & 3) + 8 * (r >> 2) + 4 * hi;
        #pragma unroll
        for (int dt = 0; dt < 2; dt++)
            Osh[row * KVP + dt * 32 + l31] = bf16_rtn(o_acc[dt][r] * inv);
    }
    __syncthreads();
    const int btq = bh >> 3, head = bh & 7;
    #pragma unroll
    for (int p = 0; p < 4; p++) {
        const int idx = p * 256 + t;
        const int row = idx >> 3, g8 = (idx & 7) * 8;
        *(uint4*)(o_bf + ((size_t)(btq * NSEQ + qt * 128 + row)) * DMODEL
                  + head * HD + g8) = *(const uint4*)&Osh[row * KVP + g8];
    }
}

// ---------------- Kernel 3: output projection (2-plane, pipelined) ----------------
__global__ __launch_bounds__(256, 3) void proj_mfma_kernel(
        const unsigned short* __restrict__ o_bf,
        const unsigned short* __restrict__ wo_bf,
        const float* __restrict__ b_out, float* __restrict__ out) {
    __shared__ __align__(16) char lds[32768];   // 2 x 16KB stages

    const int m0 = blockIdx.x * 128;
    const int f0 = blockIdx.y * 128;
    const int t = threadIdx.x;
    const int w = t >> 6, lane = t & 63, l15 = lane & 15, quad = lane >> 4;
    const int mw = (w & 1) * 64, nw = (w >> 1) * 64;

    f32x4 acc[1][4][4];
    #pragma unroll
    for (int mt = 0; mt < 4; mt++)
        #pragma unroll
        for (int nt = 0; nt < 4; nt++) acc[0][mt][nt] = (f32x4){0.f, 0.f, 0.f, 0.f};

    gemm_reg_pipe<2, 1>(o_bf, o_bf, wo_bf, lds, m0, f0, t, acc);

    float bias_v[4];
    #pragma unroll
    for (int nt = 0; nt < 4; nt++) bias_v[nt] = b_out[f0 + nw + nt * 16 + l15];
    #pragma unroll
    for (int mt = 0; mt < 4; mt++)
        #pragma unroll
        for (int nt = 0; nt < 4; nt++)
            #pragma unroll
            for (int rr = 0; rr < 4; rr++) {
                const int m = m0 + mw + mt * 16 + quad * 4 + rr;
                out[(size_t)m * DMODEL + f0 + nw + nt * 16 + l15] =
                    acc[0][mt][nt][rr] + bias_v[nt];
            }
}

extern "C" void kernel_launch(void* const* d_in, const int* in_sizes, int n_in,
                              void* d_out, int out_size, void* d_ws, size_t ws_size,
                              hipStream_t stream) {
    const float* x  = (const float*)d_in[0];
    const float* wq = (const float*)d_in[1];
    const float* wo = (const float*)d_in[2];
    const float* bo = (const float*)d_in[3];
    float* out = (float*)d_out;

    const size_t per = (size_t)BH * NSEQ * HD;   // 8,388,608 elements
    unsigned short* x_hi = (unsigned short*)d_ws;   // reused as o_bf after qkv
    unsigned short* x_lo = x_hi + per;
    unsigned short* q_bf = x_lo + per;
    unsigned short* k_bf = q_bf + per;
    unsigned short* v_th = k_bf + per;
    unsigned short* wq_bf = v_th + per;                   // 786,432 els
    unsigned short* wo_bf = wq_bf + (size_t)F3 * DMODEL;  // 262,144 els (~82 MiB total)
    unsigned short* o_bf = x_hi;   // x dead after qkv

    split_kernel<<<dim3((int)(per / 1024)), 256, 0, stream>>>(x, x_hi, x_lo);
    cvt_kernel<<<dim3(F3 * DMODEL / 1024), 256, 0, stream>>>(wq, wq_bf);
    cvt_kernel<<<dim3(DMODEL * DMODEL / 1024), 256, 0, stream>>>(wo, wo_bf);
    qkv_mfma_kernel<<<dim3(NTOK / 128, F3 / 256), 256, 0, stream>>>(
        x_hi, x_lo, wq_bf, q_bf, k_bf, v_th);
    attn_kernel<<<dim3(BH, 8), 256, 0, stream>>>(
        q_bf, k_bf, v_th, o_bf);
    proj_mfma_kernel<<<dim3(NTOK / 128, DMODEL / 128), 256, 0, stream>>>(
        o_bf, wo_bf, bo, out);
}